// Round 4
// baseline (1250.219 us; speedup 1.0000x reference)
//
#include <hip/hip_runtime.h>
#include <math.h>

// Problem constants
#define BB 64
#define LL 128
#define DD 64
#define HH 768
#define OO 256
#define NSTEPS 20

// Workspace layout (in float units):
#define WS_P     0          // 4096
#define WS_Q     4096       // 4096
#define WS_PT    8192       // 4096 (dX p transposed [d][b])
#define WS_QT    12288      // 4096
#define WS_PB    16384      // 49152
#define WS_QB    65536      // 49152
#define WS_ZG    114688     // 21*49152 = 1032192
#define WS_PART  1146880    // (fallback path) S*49152
#define WS_Y     1146880    // (mfma path) 1344*256 = 344064
#define WS_ZGHI  1490944    // 21*49152 ushort = 516096 floats
#define WS_ZGLO  2007040
#define WS_WHI   2523136    // 37748736 ushort = 18874368 floats
#define WS_WLO   21397504
#define WS_MFMA_END 40271872 // floats -> 161,087,488 bytes

typedef __attribute__((ext_vector_type(8))) short short8v;
typedef __attribute__((ext_vector_type(8))) unsigned short ushort8v;
typedef __attribute__((ext_vector_type(4))) float f32x4;

static __device__ __forceinline__ unsigned short f2bf(float x) {
    unsigned int u = __float_as_uint(x);
    unsigned int r = (u + 0x7FFFu + ((u >> 16) & 1u)) >> 16;   // RNE
    return (unsigned short)r;
}
static __device__ __forceinline__ float bf2f(unsigned short h) {
    return __uint_as_float(((unsigned int)h) << 16);
}

// ---------------------------------------------------------------------------
// Kernel 1: spline first-interval derivative coefficients.
// dX(t) = p + q*t^2 on interval 0.  M1 = sum_j (-1)^j lam^(j+1) rhs_j;
// truncated at 32 terms (lam^33 ~ 1e-19, below f64 significance).
// Also writes transposed copies pT/qT ([d][b]) for coalesced dxt fills.
// ---------------------------------------------------------------------------
__global__ void k_spline(const float* __restrict__ traj,
                         float* __restrict__ p, float* __restrict__ q,
                         float* __restrict__ pT, float* __restrict__ qT) {
    int tid = blockIdx.x * 256 + threadIdx.x;   // 0..4095
    int b = tid >> 6;
    int d = tid & 63;
    const float* y = traj + (size_t)b * LL * DD + d;

    const double LAM = 0.26794919243112270647;  // 2 - sqrt(3)
    double y0 = (double)y[0];
    double y1 = (double)y[DD];
    float fy0 = y[0];
    float fy1 = y[DD];
    double s = 0.0;
    double w = LAM;
    double sgn = 1.0;
    for (int j = 0; j < 32; ++j) {
        double y2 = (double)y[(size_t)(j + 2) * DD];
        double rhs = 6.0 * (y2 - 2.0 * y1 + y0);
        s += sgn * w * rhs;
        sgn = -sgn;
        w *= LAM;
        y0 = y1; y1 = y2;
    }
    float M1 = (float)s;
    float pp = (fy1 - fy0) - M1 / 6.0f;
    float qq = M1 * 0.5f;
    p[tid] = pp;
    q[tid] = qq;
    pT[d * 64 + b] = pp;
    qT[d * 64 + b] = qq;
}

// ---------------------------------------------------------------------------
// Kernel 2: z0 = traj[:,0,:] @ W_z0^T + b_z0 -> zg[0] (+ optional bf16 hi/lo)
//           pb[b,h] = sum_d p[b,d]*b_lin[h*64+d];  qb likewise.
// ---------------------------------------------------------------------------
__global__ void k_init(const float* __restrict__ traj,
                       const float* __restrict__ W_z0,
                       const float* __restrict__ b_z0,
                       const float* __restrict__ b_lin,
                       const float* __restrict__ p,
                       const float* __restrict__ q,
                       float* __restrict__ zg0,
                       float* __restrict__ pb,
                       float* __restrict__ qb,
                       unsigned short* __restrict__ zhi0,
                       unsigned short* __restrict__ zlo0) {
    int b = blockIdx.x;
    __shared__ float xs[64], ps[64], qs[64];
    int t = threadIdx.x;
    if (t < 64) {
        xs[t] = traj[(size_t)b * LL * DD + t];
        ps[t] = p[b * 64 + t];
        qs[t] = q[b * 64 + t];
    }
    __syncthreads();
    for (int h = t; h < HH; h += 256) {
        const float* wr = W_z0 + (size_t)h * 64;
        const float* br = b_lin + (size_t)h * 64;
        float s0 = 0.f, s1 = 0.f, s2 = 0.f;
        #pragma unroll 8
        for (int d = 0; d < 64; ++d) {
            s0 += xs[d] * wr[d];
            s1 += ps[d] * br[d];
            s2 += qs[d] * br[d];
        }
        float z = s0 + b_z0[h];
        zg0[b * HH + h] = z;
        pb[b * HH + h]  = s1;
        qb[b * HH + h]  = s2;
        if (zhi0) {
            unsigned short hh = f2bf(z);
            zhi0[b * HH + h] = hh;
            zlo0[b * HH + h] = f2bf(z - bf2f(hh));
        }
    }
}

// ---------------------------------------------------------------------------
// Kernel W: split W_lin (f32) into bf16 hi/lo arrays. Single-shot
// (18432 blocks x 256 thr x 8 elems = 37748736), no grid-stride tail.
// ---------------------------------------------------------------------------
__global__ void k_wsplit(const float* __restrict__ W,
                         unsigned short* __restrict__ Whi,
                         unsigned short* __restrict__ Wlo) {
    size_t i = ((size_t)blockIdx.x * 256 + threadIdx.x) * 8;
    const float4* s = (const float4*)(W + i);
    float4 a = s[0], bv = s[1];
    float v[8] = {a.x, a.y, a.z, a.w, bv.x, bv.y, bv.z, bv.w};
    ushort8v hi, lo;
    #pragma unroll
    for (int k = 0; k < 8; ++k) {
        unsigned short hb = f2bf(v[k]);
        hi[k] = hb;
        lo[k] = f2bf(v[k] - bf2f(hb));
    }
    *(ushort8v*)(Whi + i) = hi;
    *(ushort8v*)(Wlo + i) = lo;
}

// ---------------------------------------------------------------------------
// Kernel 3 (MFMA, v3): one Euler step, fused, 12 waves/block (3/SIMD),
// NO barriers in the K-loop: both W (A-frags) and z (B-frags) are read
// directly from global memory (z is L2/L3-resident; the 16-row x 16 B
// fragment gather is a clean 16-line vector load). Waves free-run.
// Wave wv: grp = wv&3 (K-group: chunks grp*3..grp*3+2), hl = wv>>2
// (h = blk*3+hl). Partial dX-contractions combined via LDS at the end.
// ---------------------------------------------------------------------------
__global__ __launch_bounds__(768, 3) void k_step_mfma(
        const unsigned short* __restrict__ Whi,
        const unsigned short* __restrict__ Wlo,
        const unsigned short* __restrict__ zhi,
        const unsigned short* __restrict__ zlo,
        const float* __restrict__ pT, const float* __restrict__ qT,
        const float* __restrict__ pb, const float* __restrict__ qb,
        const float* __restrict__ zprev, float* __restrict__ znext,
        unsigned short* __restrict__ znhi, unsigned short* __restrict__ znlo,
        float t, float dt) {
    __shared__ float dxt[64 * 66];                  // dX [d][b], padded stride 66
    __shared__ float partsum[4][3][64];             // [grp][h_local][b]

    int tid = threadIdx.x;
    int wv = tid >> 6;          // 0..11
    int ln = tid & 63;
    int grp = wv & 3;           // K-group
    int hl  = wv >> 2;          // 0..2
    int h   = blockIdx.x * 3 + hl;

    float t2 = t * t;
    for (int i = tid; i < 4096; i += 768) {
        int d = i >> 6, b = i & 63;
        dxt[d * 66 + b] = pT[i] + t2 * qT[i];      // coalesced reads
    }
    // (dxt is only read in the epilogue; barrier deferred to after K-loop)

    // A-frag row offsets: tile ti covers d = ti*16 + (ln&15)
    int rowk[4];
    #pragma unroll
    for (int ti = 0; ti < 4; ++ti)
        rowk[ti] = (h * 64 + ti * 16 + (ln & 15)) * HH;
    // B-frag row offsets: tile j covers b-row r = j*16 + (ln&15)
    int zr[4];
    #pragma unroll
    for (int j = 0; j < 4; ++j)
        zr[j] = (j * 16 + (ln & 15)) * HH;
    int ko = (ln >> 4) * 8;

    f32x4 acc[4][4] = {};   // [d-tile][b-tile]

    for (int it = 0; it < 3; ++it) {
        int ck = grp * 3 + it;
        #pragma unroll
        for (int ks = 0; ks < 2; ++ks) {
            int kg = ck * 64 + ks * 32 + ko;
            short8v ah[4], al[4], bh[4], bl[4];
            #pragma unroll
            for (int ti = 0; ti < 4; ++ti) {
                ah[ti] = *(const short8v*)(Whi + rowk[ti] + kg);
                al[ti] = *(const short8v*)(Wlo + rowk[ti] + kg);
            }
            #pragma unroll
            for (int j = 0; j < 4; ++j) {
                bh[j] = *(const short8v*)(zhi + zr[j] + kg);
                bl[j] = *(const short8v*)(zlo + zr[j] + kg);
            }
            #pragma unroll
            for (int ti = 0; ti < 4; ++ti) {
                #pragma unroll
                for (int j = 0; j < 4; ++j) {
                    acc[ti][j] = __builtin_amdgcn_mfma_f32_16x16x32_bf16(ah[ti], bh[j], acc[ti][j], 0, 0, 0);
                    acc[ti][j] = __builtin_amdgcn_mfma_f32_16x16x32_bf16(ah[ti], bl[j], acc[ti][j], 0, 0, 0);
                    acc[ti][j] = __builtin_amdgcn_mfma_f32_16x16x32_bf16(al[ti], bh[j], acc[ti][j], 0, 0, 0);
                }
            }
        }
    }

    __syncthreads();    // dxt writes (kernel start) visible to all waves

    // Epilogue: contract over d with dX; partial per K-group via LDS.
    // C/D layout: col(b) = ln&15, row(d within tile) = (ln>>4)*4 + reg.
    #pragma unroll
    for (int j = 0; j < 4; ++j) {
        float s = 0.f;
        #pragma unroll
        for (int ti = 0; ti < 4; ++ti) {
            #pragma unroll
            for (int rg = 0; rg < 4; ++rg) {
                int d = ti * 16 + (ln >> 4) * 4 + rg;
                s += dxt[d * 66 + (j * 16 + (ln & 15))] * acc[ti][j][rg];
            }
        }
        s += __shfl_xor(s, 16);
        s += __shfl_xor(s, 32);
        if (ln < 16) partsum[grp][hl][j * 16 + ln] = s;
    }
    __syncthreads();
    if (tid < 192) {
        int b = tid & 63;
        int hl2 = tid >> 6;
        int h2 = blockIdx.x * 3 + hl2;
        float s = partsum[0][hl2][b] + partsum[1][hl2][b]
                + partsum[2][hl2][b] + partsum[3][hl2][b];
        float inc = s + pb[b * HH + h2] + t2 * qb[b * HH + h2];
        float zn = zprev[b * HH + h2] + dt * inc;
        znext[b * HH + h2] = zn;
        unsigned short hb = f2bf(zn);
        znhi[b * HH + h2] = hb;
        znlo[b * HH + h2] = f2bf(zn - bf2f(hb));
    }
}

// ---------------------------------------------------------------------------
// Kernel Y: Y[(k,b), o] = zg[(k,b), :] @ W_out^T + b_out   (M=1344,N=256,K=768)
// ---------------------------------------------------------------------------
__global__ __launch_bounds__(256) void k_ygemm(const float* __restrict__ zg,
                                               const float* __restrict__ W_out,
                                               const float* __restrict__ b_out,
                                               float* __restrict__ Y) {
    int mt = blockIdx.x;   // 0..20
    int ot = blockIdx.y;   // 0..3
    __shared__ float at[64][68];
    __shared__ float bt[64][68];
    int tid = threadIdx.x;
    int rr = tid >> 2;
    int cc = tid & 3;
    int m0 = (tid & 15) * 4;
    int o0 = (tid >> 4) * 4;
    float acc[4][4] = {};
    for (int ch = 0; ch < 12; ++ch) {
        int k0 = ch * 64;
        {
            const float4* src = (const float4*)(zg + (size_t)(mt * 64 + rr) * HH + k0 + cc * 16);
            #pragma unroll
            for (int i = 0; i < 4; ++i) {
                float4 v = src[i];
                int kk = cc * 16 + i * 4;
                at[kk + 0][rr] = v.x; at[kk + 1][rr] = v.y;
                at[kk + 2][rr] = v.z; at[kk + 3][rr] = v.w;
            }
        }
        {
            const float4* src = (const float4*)(W_out + (size_t)(ot * 64 + rr) * HH + k0 + cc * 16);
            #pragma unroll
            for (int i = 0; i < 4; ++i) {
                float4 v = src[i];
                int kk = cc * 16 + i * 4;
                bt[kk + 0][rr] = v.x; bt[kk + 1][rr] = v.y;
                bt[kk + 2][rr] = v.z; bt[kk + 3][rr] = v.w;
            }
        }
        __syncthreads();
        #pragma unroll
        for (int kk = 0; kk < 64; ++kk) {
            float4 aa = *(const float4*)&at[kk][m0];
            float4 ba = *(const float4*)&bt[kk][o0];
            acc[0][0] += aa.x * ba.x; acc[0][1] += aa.x * ba.y;
            acc[0][2] += aa.x * ba.z; acc[0][3] += aa.x * ba.w;
            acc[1][0] += aa.y * ba.x; acc[1][1] += aa.y * ba.y;
            acc[1][2] += aa.y * ba.z; acc[1][3] += aa.y * ba.w;
            acc[2][0] += aa.z * ba.x; acc[2][1] += aa.z * ba.y;
            acc[2][2] += aa.z * ba.z; acc[2][3] += aa.z * ba.w;
            acc[3][0] += aa.w * ba.x; acc[3][1] += aa.w * ba.y;
            acc[3][2] += aa.w * ba.z; acc[3][3] += aa.w * ba.w;
        }
        __syncthreads();
    }
    #pragma unroll
    for (int i = 0; i < 4; ++i) {
        float* dst = Y + (size_t)(mt * 64 + m0 + i) * OO + ot * 64 + o0;
        #pragma unroll
        for (int jj = 0; jj < 4; ++jj)
            dst[jj] = acc[i][jj] + b_out[ot * 64 + o0 + jj];
    }
}

// ---------------------------------------------------------------------------
// Kernel I: out[(b,l), o] = (1-w_l)*Y[(j,b),o] + w_l*Y[(j+1,b),o]
// ---------------------------------------------------------------------------
__global__ void k_interp(const float* __restrict__ Y, float* __restrict__ out) {
    int idx = blockIdx.x * 256 + threadIdx.x;   // 0..524287, one float4 each
    int m = idx >> 6;
    int o4 = idx & 63;
    int b = m >> 7, l = m & 127;
    float ts = (l == 127) ? 1.0f : (float)l * (1.0f / 127.0f);
    int j = (int)(ts * 20.0f);
    if (j > 19) j = 19;
    if (j < 0) j = 0;
    float gj  = (float)j * 0.05f;
    float gj1 = (j == 19) ? 1.0f : (float)(j + 1) * 0.05f;
    float w = (ts - gj) / (gj1 - gj);
    float4 A = *((const float4*)(Y + (size_t)(j * 64 + b) * OO) + o4);
    float4 Bv = *((const float4*)(Y + (size_t)((j + 1) * 64 + b) * OO) + o4);
    float4 r;
    r.x = (1.0f - w) * A.x + w * Bv.x;
    r.y = (1.0f - w) * A.y + w * Bv.y;
    r.z = (1.0f - w) * A.z + w * Bv.z;
    r.w = (1.0f - w) * A.w + w * Bv.w;
    ((float4*)out)[idx] = r;
}

// ===========================================================================
// FALLBACK PATH (round-1 kernels, known-passing) — used if ws_size too small.
// ===========================================================================
__global__ __launch_bounds__(256) void k_step_gemm(
        const float* __restrict__ W_lin,
        const float* __restrict__ p,
        const float* __restrict__ q,
        const float* __restrict__ z,
        float* __restrict__ part,
        int dpb, float t) {
    int nt = blockIdx.x;
    int sg = blockIdx.y;
    __shared__ float zt[64][68];
    __shared__ float wt[64][68];
    int tid = threadIdx.x;
    int rr = tid >> 2;
    int cc = tid & 3;
    int b0 = (tid & 15) * 4;
    int h0 = (tid >> 4) * 4;
    float accz[4][4] = {};
    for (int dd = 0; dd < dpb; ++dd) {
        int d = sg * dpb + dd;
        float accf[4][4] = {};
        for (int ch = 0; ch < 12; ++ch) {
            int k0 = ch * 64;
            {
                const float4* src = (const float4*)(z + (size_t)rr * HH + k0 + cc * 16);
                #pragma unroll
                for (int i = 0; i < 4; ++i) {
                    float4 v = src[i];
                    int kk = cc * 16 + i * 4;
                    zt[kk + 0][rr] = v.x; zt[kk + 1][rr] = v.y;
                    zt[kk + 2][rr] = v.z; zt[kk + 3][rr] = v.w;
                }
            }
            {
                const float4* src = (const float4*)(W_lin +
                    ((size_t)(nt * 64 + rr) * 64 + d) * HH + k0 + cc * 16);
                #pragma unroll
                for (int i = 0; i < 4; ++i) {
                    float4 v = src[i];
                    int kk = cc * 16 + i * 4;
                    wt[kk + 0][rr] = v.x; wt[kk + 1][rr] = v.y;
                    wt[kk + 2][rr] = v.z; wt[kk + 3][rr] = v.w;
                }
            }
            __syncthreads();
            #pragma unroll
            for (int kk = 0; kk < 64; ++kk) {
                float4 za = *(const float4*)&zt[kk][b0];
                float4 wa = *(const float4*)&wt[kk][h0];
                accf[0][0] += za.x * wa.x; accf[0][1] += za.x * wa.y;
                accf[0][2] += za.x * wa.z; accf[0][3] += za.x * wa.w;
                accf[1][0] += za.y * wa.x; accf[1][1] += za.y * wa.y;
                accf[1][2] += za.y * wa.z; accf[1][3] += za.y * wa.w;
                accf[2][0] += za.z * wa.x; accf[2][1] += za.z * wa.y;
                accf[2][2] += za.z * wa.z; accf[2][3] += za.z * wa.w;
                accf[3][0] += za.w * wa.x; accf[3][1] += za.w * wa.y;
                accf[3][2] += za.w * wa.z; accf[3][3] += za.w * wa.w;
            }
            __syncthreads();
        }
        #pragma unroll
        for (int i = 0; i < 4; ++i) {
            float pv = p[(b0 + i) * 64 + d];
            float qv = q[(b0 + i) * 64 + d];
            float dx = pv + (qv * t) * t;
            #pragma unroll
            for (int j = 0; j < 4; ++j) accz[i][j] += dx * accf[i][j];
        }
    }
    #pragma unroll
    for (int i = 0; i < 4; ++i) {
        float* dst = part + (size_t)sg * (BB * HH) + (size_t)(b0 + i) * HH + nt * 64 + h0;
        dst[0] = accz[i][0]; dst[1] = accz[i][1];
        dst[2] = accz[i][2]; dst[3] = accz[i][3];
    }
}

__global__ void k_step_update(const float* __restrict__ part,
                              const float* __restrict__ pb,
                              const float* __restrict__ qb,
                              const float* __restrict__ zprev,
                              float* __restrict__ znext,
                              int S, float t, float dt) {
    int idx = blockIdx.x * 256 + threadIdx.x;
    float s = 0.f;
    for (int i = 0; i < S; ++i) s += part[(size_t)i * (BB * HH) + idx];
    float t2 = t * t;
    znext[idx] = zprev[idx] + dt * (s + pb[idx] + t2 * qb[idx]);
}

__global__ __launch_bounds__(256) void k_out(const float* __restrict__ zg,
                                             const float* __restrict__ W_out,
                                             const float* __restrict__ b_out,
                                             float* __restrict__ out) {
    int mt = blockIdx.x;
    int ot = blockIdx.y;
    __shared__ float at[64][68];
    __shared__ float bt[64][68];
    int tid = threadIdx.x;
    int rr = tid >> 2;
    int cc = tid & 3;
    int m0 = (tid & 15) * 4;
    int o0 = (tid >> 4) * 4;
    int m = mt * 64 + rr;
    int b = m >> 7;
    int l = m & 127;
    float ts = (l == 127) ? 1.0f : (float)l * (1.0f / 127.0f);
    int j = (int)(ts * 20.0f);
    if (j > 19) j = 19;
    if (j < 0) j = 0;
    float gj  = (float)j * 0.05f;
    float gj1 = (j == 19) ? 1.0f : (float)(j + 1) * 0.05f;
    float w = (ts - gj) / (gj1 - gj);
    const float* zA = zg + (size_t)j * (BB * HH) + (size_t)b * HH;
    const float* zB = zg + (size_t)(j + 1) * (BB * HH) + (size_t)b * HH;
    float acc[4][4] = {};
    for (int ch = 0; ch < 12; ++ch) {
        int k0 = ch * 64;
        {
            #pragma unroll
            for (int i = 0; i < 4; ++i) {
                int kk = cc * 16 + i * 4;
                float4 va = *(const float4*)(zA + k0 + kk);
                float4 vb = *(const float4*)(zB + k0 + kk);
                at[kk + 0][rr] = (1.0f - w) * va.x + w * vb.x;
                at[kk + 1][rr] = (1.0f - w) * va.y + w * vb.y;
                at[kk + 2][rr] = (1.0f - w) * va.z + w * vb.z;
                at[kk + 3][rr] = (1.0f - w) * va.w + w * vb.w;
            }
        }
        {
            const float4* src = (const float4*)(W_out + (size_t)(ot * 64 + rr) * HH + k0 + cc * 16);
            #pragma unroll
            for (int i = 0; i < 4; ++i) {
                float4 v = src[i];
                int kk = cc * 16 + i * 4;
                bt[kk + 0][rr] = v.x; bt[kk + 1][rr] = v.y;
                bt[kk + 2][rr] = v.z; bt[kk + 3][rr] = v.w;
            }
        }
        __syncthreads();
        #pragma unroll
        for (int kk = 0; kk < 64; ++kk) {
            float4 aa = *(const float4*)&at[kk][m0];
            float4 ba = *(const float4*)&bt[kk][o0];
            acc[0][0] += aa.x * ba.x; acc[0][1] += aa.x * ba.y;
            acc[0][2] += aa.x * ba.z; acc[0][3] += aa.x * ba.w;
            acc[1][0] += aa.y * ba.x; acc[1][1] += aa.y * ba.y;
            acc[1][2] += aa.y * ba.z; acc[1][3] += aa.y * ba.w;
            acc[2][0] += aa.z * ba.x; acc[2][1] += aa.z * ba.y;
            acc[2][2] += aa.z * ba.z; acc[2][3] += aa.z * ba.w;
            acc[3][0] += aa.w * ba.x; acc[3][1] += aa.w * ba.y;
            acc[3][2] += aa.w * ba.z; acc[3][3] += aa.w * ba.w;
        }
        __syncthreads();
    }
    #pragma unroll
    for (int i = 0; i < 4; ++i) {
        float* dst = out + (size_t)(mt * 64 + m0 + i) * OO + ot * 64 + o0;
        #pragma unroll
        for (int jj = 0; jj < 4; ++jj)
            dst[jj] = acc[i][jj] + b_out[ot * 64 + o0 + jj];
    }
}

// ---------------------------------------------------------------------------
extern "C" void kernel_launch(void* const* d_in, const int* in_sizes, int n_in,
                              void* d_out, int out_size, void* d_ws, size_t ws_size,
                              hipStream_t stream) {
    const float* traj  = (const float*)d_in[0];
    const float* W_lin = (const float*)d_in[2];
    const float* b_lin = (const float*)d_in[3];
    const float* W_out = (const float*)d_in[4];
    const float* b_out = (const float*)d_in[5];
    const float* W_z0  = (const float*)d_in[6];
    const float* b_z0  = (const float*)d_in[7];

    float* ws = (float*)d_ws;
    float* p  = ws + WS_P;
    float* q  = ws + WS_Q;
    float* pT = ws + WS_PT;
    float* qT = ws + WS_QT;
    float* pb = ws + WS_PB;
    float* qb = ws + WS_QB;
    float* zg = ws + WS_ZG;

    float g[NSTEPS + 1];
    for (int k = 0; k <= NSTEPS; ++k) g[k] = (float)k * 0.05f;
    g[NSTEPS] = 1.0f;

    bool mfma_path = ws_size >= (size_t)WS_MFMA_END * 4;

    if (mfma_path) {
        float* Y = ws + WS_Y;
        unsigned short* zghi = (unsigned short*)(ws + WS_ZGHI);
        unsigned short* zglo = (unsigned short*)(ws + WS_ZGLO);
        unsigned short* Whi  = (unsigned short*)(ws + WS_WHI);
        unsigned short* Wlo  = (unsigned short*)(ws + WS_WLO);

        k_spline<<<16, 256, 0, stream>>>(traj, p, q, pT, qT);
        k_init<<<BB, 256, 0, stream>>>(traj, W_z0, b_z0, b_lin, p, q, zg, pb, qb,
                                       zghi, zglo);
        k_wsplit<<<18432, 256, 0, stream>>>(W_lin, Whi, Wlo);

        for (int k = 0; k < NSTEPS; ++k) {
            float t  = g[k];
            float dt = g[k + 1] - g[k];
            k_step_mfma<<<256, 768, 0, stream>>>(
                Whi, Wlo,
                zghi + (size_t)k * (BB * HH), zglo + (size_t)k * (BB * HH),
                pT, qT, pb, qb,
                zg + (size_t)k * (BB * HH), zg + (size_t)(k + 1) * (BB * HH),
                zghi + (size_t)(k + 1) * (BB * HH), zglo + (size_t)(k + 1) * (BB * HH),
                t, dt);
        }
        k_ygemm<<<dim3(21, 4), 256, 0, stream>>>(zg, W_out, b_out, Y);
        k_interp<<<2048, 256, 0, stream>>>(Y, (float*)d_out);
    } else {
        float* part = ws + WS_PART;
        size_t base_bytes = (size_t)WS_PART * 4;
        int S = 64;
        while (S > 1 && base_bytes + (size_t)S * (BB * HH) * 4 > ws_size) S >>= 1;
        int dpb = 64 / S;

        k_spline<<<16, 256, 0, stream>>>(traj, p, q, pT, qT);
        k_init<<<BB, 256, 0, stream>>>(traj, W_z0, b_z0, b_lin, p, q, zg, pb, qb,
                                       nullptr, nullptr);
        for (int k = 0; k < NSTEPS; ++k) {
            float t  = g[k];
            float dt = g[k + 1] - g[k];
            const float* zprev = zg + (size_t)k * (BB * HH);
            float* znext       = zg + (size_t)(k + 1) * (BB * HH);
            k_step_gemm<<<dim3(12, S), 256, 0, stream>>>(W_lin, p, q, zprev, part, dpb, t);
            k_step_update<<<192, 256, 0, stream>>>(part, pb, qb, zprev, znext, S, t, dt);
        }
        k_out<<<dim3(128, 4), 256, 0, stream>>>(zg, W_out, b_out, (float*)d_out);
    }
}

// Round 5
// 847.458 us; speedup vs baseline: 1.4753x; 1.4753x over previous
//
#include <hip/hip_runtime.h>
#include <math.h>

// Problem constants
#define BB 64
#define LL 128
#define DD 64
#define HH 768
#define OO 256
#define NSTEPS 20

// Workspace layout (in float units):
#define WS_P     0          // 4096
#define WS_Q     4096       // 4096
#define WS_PT    8192       // 4096 (dX p transposed [d][b])
#define WS_QT    12288      // 4096
#define WS_PB    16384      // 49152
#define WS_QB    65536      // 49152
#define WS_ZG    114688     // 21*49152 = 1032192
#define WS_PART  1146880    // (fallback path) S*49152
#define WS_Y     1146880    // (mfma path) 1344*256 = 344064
#define WS_ZGHI  1490944    // 21*49152 ushort = 516096 floats
#define WS_ZGLO  2007040
#define WS_WHI   2523136    // 37748736 ushort = 18874368 floats
#define WS_WLO   21397504
#define WS_MFMA_END 40271872 // floats -> 161,087,488 bytes

typedef __attribute__((ext_vector_type(8))) short short8v;
typedef __attribute__((ext_vector_type(8))) unsigned short ushort8v;
typedef __attribute__((ext_vector_type(4))) float f32x4;

static __device__ __forceinline__ unsigned short f2bf(float x) {
    unsigned int u = __float_as_uint(x);
    unsigned int r = (u + 0x7FFFu + ((u >> 16) & 1u)) >> 16;   // RNE
    return (unsigned short)r;
}
static __device__ __forceinline__ float bf2f(unsigned short h) {
    return __uint_as_float(((unsigned int)h) << 16);
}

// Packed z index: element (b, k) -> fragment-linear layout [ck][ks][j][lane][8]
// so the step kernel's B-loads are base + lane*16B (fully coalesced).
static __device__ __forceinline__ int zpk(int b, int k) {
    int ck = k >> 6, km = k & 63, ks = km >> 5, lh = (km & 31) >> 3, e = k & 7;
    int j = b >> 4, lr = b & 15;
    return ((((ck * 2 + ks) * 4 + j) * 64) + lh * 16 + lr) * 8 + e;
}

// ---------------------------------------------------------------------------
// Kernel 1: spline first-interval derivative coefficients.
// dX(t) = p + q*t^2 on interval 0.  M1 = sum_j (-1)^j lam^(j+1) rhs_j;
// truncated at 32 terms (lam^33 ~ 1e-19, below f64 significance).
// Also writes transposed copies pT/qT ([d][b]) for coalesced dxt fills.
// ---------------------------------------------------------------------------
__global__ void k_spline(const float* __restrict__ traj,
                         float* __restrict__ p, float* __restrict__ q,
                         float* __restrict__ pT, float* __restrict__ qT) {
    int tid = blockIdx.x * 256 + threadIdx.x;   // 0..4095
    int b = tid >> 6;
    int d = tid & 63;
    const float* y = traj + (size_t)b * LL * DD + d;

    const double LAM = 0.26794919243112270647;  // 2 - sqrt(3)
    double y0 = (double)y[0];
    double y1 = (double)y[DD];
    float fy0 = y[0];
    float fy1 = y[DD];
    double s = 0.0;
    double w = LAM;
    double sgn = 1.0;
    for (int j = 0; j < 32; ++j) {
        double y2 = (double)y[(size_t)(j + 2) * DD];
        double rhs = 6.0 * (y2 - 2.0 * y1 + y0);
        s += sgn * w * rhs;
        sgn = -sgn;
        w *= LAM;
        y0 = y1; y1 = y2;
    }
    float M1 = (float)s;
    float pp = (fy1 - fy0) - M1 / 6.0f;
    float qq = M1 * 0.5f;
    p[tid] = pp;
    q[tid] = qq;
    pT[d * 64 + b] = pp;
    qT[d * 64 + b] = qq;
}

// ---------------------------------------------------------------------------
// Kernel 2: z0 = traj[:,0,:] @ W_z0^T + b_z0 -> zg[0] (+ packed bf16 hi/lo)
//           pb[b,h] = sum_d p[b,d]*b_lin[h*64+d];  qb likewise.
// ---------------------------------------------------------------------------
__global__ void k_init(const float* __restrict__ traj,
                       const float* __restrict__ W_z0,
                       const float* __restrict__ b_z0,
                       const float* __restrict__ b_lin,
                       const float* __restrict__ p,
                       const float* __restrict__ q,
                       float* __restrict__ zg0,
                       float* __restrict__ pb,
                       float* __restrict__ qb,
                       unsigned short* __restrict__ zhi0,
                       unsigned short* __restrict__ zlo0) {
    int b = blockIdx.x;
    __shared__ float xs[64], ps[64], qs[64];
    int t = threadIdx.x;
    if (t < 64) {
        xs[t] = traj[(size_t)b * LL * DD + t];
        ps[t] = p[b * 64 + t];
        qs[t] = q[b * 64 + t];
    }
    __syncthreads();
    for (int h = t; h < HH; h += 256) {
        const float* wr = W_z0 + (size_t)h * 64;
        const float* br = b_lin + (size_t)h * 64;
        float s0 = 0.f, s1 = 0.f, s2 = 0.f;
        #pragma unroll 8
        for (int d = 0; d < 64; ++d) {
            s0 += xs[d] * wr[d];
            s1 += ps[d] * br[d];
            s2 += qs[d] * br[d];
        }
        float z = s0 + b_z0[h];
        zg0[b * HH + h] = z;
        pb[b * HH + h]  = s1;
        qb[b * HH + h]  = s2;
        if (zhi0) {
            unsigned short hh = f2bf(z);
            int zi = zpk(b, h);
            zhi0[zi] = hh;
            zlo0[zi] = f2bf(z - bf2f(hh));
        }
    }
}

// ---------------------------------------------------------------------------
// Kernel W: split W_lin (f32) into bf16 hi/lo arrays, PACKED fragment-linear:
// chunk c = (((h*12 + ck)*2 + ks)*4 + ti)*64 + ln holds
//   W[row = h*64 + ti*16 + (ln&15)][k = ck*64 + ks*32 + (ln>>4)*8 .. +8].
// Writes are perfectly sequential (thread = chunk); reads cover full 128-B
// lines (16 rows x 128 B contiguous per 2 instructions).
// ---------------------------------------------------------------------------
__global__ void k_wsplit(const float* __restrict__ W,
                         unsigned short* __restrict__ Whi,
                         unsigned short* __restrict__ Wlo) {
    int c = blockIdx.x * 256 + threadIdx.x;     // chunk id, 0..4718591
    int ln = c & 63;
    int r1 = c >> 6;
    int ti = r1 & 3;
    int r2 = r1 >> 2;
    int ks = r2 & 1;
    int r3 = r2 >> 1;
    int ck = r3 % 12;
    int h  = r3 / 12;
    int lr = ln & 15, lh = ln >> 4;
    int row = h * 64 + ti * 16 + lr;
    int k   = ck * 64 + ks * 32 + lh * 8;
    const float4* s = (const float4*)(W + (size_t)row * HH + k);
    float4 a = s[0], bv = s[1];
    float v[8] = {a.x, a.y, a.z, a.w, bv.x, bv.y, bv.z, bv.w};
    ushort8v hi, lo;
    #pragma unroll
    for (int e = 0; e < 8; ++e) {
        unsigned short hb = f2bf(v[e]);
        hi[e] = hb;
        lo[e] = f2bf(v[e] - bf2f(hb));
    }
    *(ushort8v*)(Whi + (size_t)c * 8) = hi;
    *(ushort8v*)(Wlo + (size_t)c * 8) = lo;
}

// ---------------------------------------------------------------------------
// Kernel 3 (MFMA, v4): one Euler step, fused, 12 waves/block (3/SIMD),
// no barriers in the K-loop. W and z are PRE-PACKED fragment-linear, so
// every A/B load is base + lane*16B: fully-coalesced 1 KB per instruction,
// sequential across ti/ks/ck — W streams at memory rate instead of the
// ~2.7 TB/s gather wall. Wave wv: grp = wv&3 (K chunks grp*3..grp*3+2),
// hl = wv>>2 (h = blk*3+hl). Partials combined via LDS at the end.
// ---------------------------------------------------------------------------
__global__ __launch_bounds__(768, 3) void k_step_mfma(
        const unsigned short* __restrict__ Whi,
        const unsigned short* __restrict__ Wlo,
        const unsigned short* __restrict__ zhi,
        const unsigned short* __restrict__ zlo,
        const float* __restrict__ pT, const float* __restrict__ qT,
        const float* __restrict__ pb, const float* __restrict__ qb,
        const float* __restrict__ zprev, float* __restrict__ znext,
        unsigned short* __restrict__ znhi, unsigned short* __restrict__ znlo,
        float t, float dt) {
    __shared__ float dxt[64 * 66];                  // dX [d][b], padded stride 66
    __shared__ float partsum[4][3][64];             // [grp][h_local][b]

    int tid = threadIdx.x;
    int wv = tid >> 6;          // 0..11
    int ln = tid & 63;
    int grp = wv & 3;           // K-group
    int hl  = wv >> 2;          // 0..2
    int h   = blockIdx.x * 3 + hl;

    float t2 = t * t;
    for (int i = tid; i < 4096; i += 768) {
        int d = i >> 6, b = i & 63;
        dxt[d * 66 + b] = pT[i] + t2 * qT[i];      // coalesced reads
    }
    // (dxt is only read in the epilogue; barrier deferred to after K-loop)

    f32x4 acc[4][4] = {};   // [d-tile][b-tile]

    for (int it = 0; it < 3; ++it) {
        int ck = grp * 3 + it;
        #pragma unroll
        for (int ks = 0; ks < 2; ++ks) {
            // W base for (h, ck, ks): 4 ti-chunks of 512 ushorts each
            size_t wb = ((((size_t)h * 12 + ck) * 2 + ks) * 4) * 512 + ln * 8;
            // z base for (ck, ks): 4 j-chunks of 512 ushorts each
            int zb = ((ck * 2 + ks) * 4) * 512 + ln * 8;
            short8v ah[4], al[4], bh[4], bl[4];
            #pragma unroll
            for (int ti = 0; ti < 4; ++ti) {
                ah[ti] = *(const short8v*)(Whi + wb + ti * 512);
                al[ti] = *(const short8v*)(Wlo + wb + ti * 512);
            }
            #pragma unroll
            for (int j = 0; j < 4; ++j) {
                bh[j] = *(const short8v*)(zhi + zb + j * 512);
                bl[j] = *(const short8v*)(zlo + zb + j * 512);
            }
            #pragma unroll
            for (int ti = 0; ti < 4; ++ti) {
                #pragma unroll
                for (int j = 0; j < 4; ++j) {
                    acc[ti][j] = __builtin_amdgcn_mfma_f32_16x16x32_bf16(ah[ti], bh[j], acc[ti][j], 0, 0, 0);
                    acc[ti][j] = __builtin_amdgcn_mfma_f32_16x16x32_bf16(ah[ti], bl[j], acc[ti][j], 0, 0, 0);
                    acc[ti][j] = __builtin_amdgcn_mfma_f32_16x16x32_bf16(al[ti], bh[j], acc[ti][j], 0, 0, 0);
                }
            }
        }
    }

    __syncthreads();    // dxt writes (kernel start) visible to all waves

    // Epilogue: contract over d with dX; partial per K-group via LDS.
    // C/D layout: col(b) = ln&15, row(d within tile) = (ln>>4)*4 + reg.
    #pragma unroll
    for (int j = 0; j < 4; ++j) {
        float s = 0.f;
        #pragma unroll
        for (int ti = 0; ti < 4; ++ti) {
            #pragma unroll
            for (int rg = 0; rg < 4; ++rg) {
                int d = ti * 16 + (ln >> 4) * 4 + rg;
                s += dxt[d * 66 + (j * 16 + (ln & 15))] * acc[ti][j][rg];
            }
        }
        s += __shfl_xor(s, 16);
        s += __shfl_xor(s, 32);
        if (ln < 16) partsum[grp][hl][j * 16 + ln] = s;
    }
    __syncthreads();
    if (tid < 192) {
        int b = tid & 63;
        int hl2 = tid >> 6;
        int h2 = blockIdx.x * 3 + hl2;
        float s = partsum[0][hl2][b] + partsum[1][hl2][b]
                + partsum[2][hl2][b] + partsum[3][hl2][b];
        float inc = s + pb[b * HH + h2] + t2 * qb[b * HH + h2];
        float zn = zprev[b * HH + h2] + dt * inc;
        znext[b * HH + h2] = zn;
        unsigned short hb = f2bf(zn);
        int zi = zpk(b, h2);
        znhi[zi] = hb;
        znlo[zi] = f2bf(zn - bf2f(hb));
    }
}

// ---------------------------------------------------------------------------
// Kernel Y: Y[(k,b), o] = zg[(k,b), :] @ W_out^T + b_out   (M=1344,N=256,K=768)
// ---------------------------------------------------------------------------
__global__ __launch_bounds__(256) void k_ygemm(const float* __restrict__ zg,
                                               const float* __restrict__ W_out,
                                               const float* __restrict__ b_out,
                                               float* __restrict__ Y) {
    int mt = blockIdx.x;   // 0..20
    int ot = blockIdx.y;   // 0..3
    __shared__ float at[64][68];
    __shared__ float bt[64][68];
    int tid = threadIdx.x;
    int rr = tid >> 2;
    int cc = tid & 3;
    int m0 = (tid & 15) * 4;
    int o0 = (tid >> 4) * 4;
    float acc[4][4] = {};
    for (int ch = 0; ch < 12; ++ch) {
        int k0 = ch * 64;
        {
            const float4* src = (const float4*)(zg + (size_t)(mt * 64 + rr) * HH + k0 + cc * 16);
            #pragma unroll
            for (int i = 0; i < 4; ++i) {
                float4 v = src[i];
                int kk = cc * 16 + i * 4;
                at[kk + 0][rr] = v.x; at[kk + 1][rr] = v.y;
                at[kk + 2][rr] = v.z; at[kk + 3][rr] = v.w;
            }
        }
        {
            const float4* src = (const float4*)(W_out + (size_t)(ot * 64 + rr) * HH + k0 + cc * 16);
            #pragma unroll
            for (int i = 0; i < 4; ++i) {
                float4 v = src[i];
                int kk = cc * 16 + i * 4;
                bt[kk + 0][rr] = v.x; bt[kk + 1][rr] = v.y;
                bt[kk + 2][rr] = v.z; bt[kk + 3][rr] = v.w;
            }
        }
        __syncthreads();
        #pragma unroll
        for (int kk = 0; kk < 64; ++kk) {
            float4 aa = *(const float4*)&at[kk][m0];
            float4 ba = *(const float4*)&bt[kk][o0];
            acc[0][0] += aa.x * ba.x; acc[0][1] += aa.x * ba.y;
            acc[0][2] += aa.x * ba.z; acc[0][3] += aa.x * ba.w;
            acc[1][0] += aa.y * ba.x; acc[1][1] += aa.y * ba.y;
            acc[1][2] += aa.y * ba.z; acc[1][3] += aa.y * ba.w;
            acc[2][0] += aa.z * ba.x; acc[2][1] += aa.z * ba.y;
            acc[2][2] += aa.z * ba.z; acc[2][3] += aa.z * ba.w;
            acc[3][0] += aa.w * ba.x; acc[3][1] += aa.w * ba.y;
            acc[3][2] += aa.w * ba.z; acc[3][3] += aa.w * ba.w;
        }
        __syncthreads();
    }
    #pragma unroll
    for (int i = 0; i < 4; ++i) {
        float* dst = Y + (size_t)(mt * 64 + m0 + i) * OO + ot * 64 + o0;
        #pragma unroll
        for (int jj = 0; jj < 4; ++jj)
            dst[jj] = acc[i][jj] + b_out[ot * 64 + o0 + jj];
    }
}

// ---------------------------------------------------------------------------
// Kernel I: out[(b,l), o] = (1-w_l)*Y[(j,b),o] + w_l*Y[(j+1,b),o]
// ---------------------------------------------------------------------------
__global__ void k_interp(const float* __restrict__ Y, float* __restrict__ out) {
    int idx = blockIdx.x * 256 + threadIdx.x;   // 0..524287, one float4 each
    int m = idx >> 6;
    int o4 = idx & 63;
    int b = m >> 7, l = m & 127;
    float ts = (l == 127) ? 1.0f : (float)l * (1.0f / 127.0f);
    int j = (int)(ts * 20.0f);
    if (j > 19) j = 19;
    if (j < 0) j = 0;
    float gj  = (float)j * 0.05f;
    float gj1 = (j == 19) ? 1.0f : (float)(j + 1) * 0.05f;
    float w = (ts - gj) / (gj1 - gj);
    float4 A = *((const float4*)(Y + (size_t)(j * 64 + b) * OO) + o4);
    float4 Bv = *((const float4*)(Y + (size_t)((j + 1) * 64 + b) * OO) + o4);
    float4 r;
    r.x = (1.0f - w) * A.x + w * Bv.x;
    r.y = (1.0f - w) * A.y + w * Bv.y;
    r.z = (1.0f - w) * A.z + w * Bv.z;
    r.w = (1.0f - w) * A.w + w * Bv.w;
    ((float4*)out)[idx] = r;
}

// ===========================================================================
// FALLBACK PATH (round-1 kernels, known-passing) — used if ws_size too small.
// ===========================================================================
__global__ __launch_bounds__(256) void k_step_gemm(
        const float* __restrict__ W_lin,
        const float* __restrict__ p,
        const float* __restrict__ q,
        const float* __restrict__ z,
        float* __restrict__ part,
        int dpb, float t) {
    int nt = blockIdx.x;
    int sg = blockIdx.y;
    __shared__ float zt[64][68];
    __shared__ float wt[64][68];
    int tid = threadIdx.x;
    int rr = tid >> 2;
    int cc = tid & 3;
    int b0 = (tid & 15) * 4;
    int h0 = (tid >> 4) * 4;
    float accz[4][4] = {};
    for (int dd = 0; dd < dpb; ++dd) {
        int d = sg * dpb + dd;
        float accf[4][4] = {};
        for (int ch = 0; ch < 12; ++ch) {
            int k0 = ch * 64;
            {
                const float4* src = (const float4*)(z + (size_t)rr * HH + k0 + cc * 16);
                #pragma unroll
                for (int i = 0; i < 4; ++i) {
                    float4 v = src[i];
                    int kk = cc * 16 + i * 4;
                    zt[kk + 0][rr] = v.x; zt[kk + 1][rr] = v.y;
                    zt[kk + 2][rr] = v.z; zt[kk + 3][rr] = v.w;
                }
            }
            {
                const float4* src = (const float4*)(W_lin +
                    ((size_t)(nt * 64 + rr) * 64 + d) * HH + k0 + cc * 16);
                #pragma unroll
                for (int i = 0; i < 4; ++i) {
                    float4 v = src[i];
                    int kk = cc * 16 + i * 4;
                    wt[kk + 0][rr] = v.x; wt[kk + 1][rr] = v.y;
                    wt[kk + 2][rr] = v.z; wt[kk + 3][rr] = v.w;
                }
            }
            __syncthreads();
            #pragma unroll
            for (int kk = 0; kk < 64; ++kk) {
                float4 za = *(const float4*)&zt[kk][b0];
                float4 wa = *(const float4*)&wt[kk][h0];
                accf[0][0] += za.x * wa.x; accf[0][1] += za.x * wa.y;
                accf[0][2] += za.x * wa.z; accf[0][3] += za.x * wa.w;
                accf[1][0] += za.y * wa.x; accf[1][1] += za.y * wa.y;
                accf[1][2] += za.y * wa.z; accf[1][3] += za.y * wa.w;
                accf[2][0] += za.z * wa.x; accf[2][1] += za.z * wa.y;
                accf[2][2] += za.z * wa.z; accf[2][3] += za.z * wa.w;
                accf[3][0] += za.w * wa.x; accf[3][1] += za.w * wa.y;
                accf[3][2] += za.w * wa.z; accf[3][3] += za.w * wa.w;
            }
            __syncthreads();
        }
        #pragma unroll
        for (int i = 0; i < 4; ++i) {
            float pv = p[(b0 + i) * 64 + d];
            float qv = q[(b0 + i) * 64 + d];
            float dx = pv + (qv * t) * t;
            #pragma unroll
            for (int j = 0; j < 4; ++j) accz[i][j] += dx * accf[i][j];
        }
    }
    #pragma unroll
    for (int i = 0; i < 4; ++i) {
        float* dst = part + (size_t)sg * (BB * HH) + (size_t)(b0 + i) * HH + nt * 64 + h0;
        dst[0] = accz[i][0]; dst[1] = accz[i][1];
        dst[2] = accz[i][2]; dst[3] = accz[i][3];
    }
}

__global__ void k_step_update(const float* __restrict__ part,
                              const float* __restrict__ pb,
                              const float* __restrict__ qb,
                              const float* __restrict__ zprev,
                              float* __restrict__ znext,
                              int S, float t, float dt) {
    int idx = blockIdx.x * 256 + threadIdx.x;
    float s = 0.f;
    for (int i = 0; i < S; ++i) s += part[(size_t)i * (BB * HH) + idx];
    float t2 = t * t;
    znext[idx] = zprev[idx] + dt * (s + pb[idx] + t2 * qb[idx]);
}

__global__ __launch_bounds__(256) void k_out(const float* __restrict__ zg,
                                             const float* __restrict__ W_out,
                                             const float* __restrict__ b_out,
                                             float* __restrict__ out) {
    int mt = blockIdx.x;
    int ot = blockIdx.y;
    __shared__ float at[64][68];
    __shared__ float bt[64][68];
    int tid = threadIdx.x;
    int rr = tid >> 2;
    int cc = tid & 3;
    int m0 = (tid & 15) * 4;
    int o0 = (tid >> 4) * 4;
    int m = mt * 64 + rr;
    int b = m >> 7;
    int l = m & 127;
    float ts = (l == 127) ? 1.0f : (float)l * (1.0f / 127.0f);
    int j = (int)(ts * 20.0f);
    if (j > 19) j = 19;
    if (j < 0) j = 0;
    float gj  = (float)j * 0.05f;
    float gj1 = (j == 19) ? 1.0f : (float)(j + 1) * 0.05f;
    float w = (ts - gj) / (gj1 - gj);
    const float* zA = zg + (size_t)j * (BB * HH) + (size_t)b * HH;
    const float* zB = zg + (size_t)(j + 1) * (BB * HH) + (size_t)b * HH;
    float acc[4][4] = {};
    for (int ch = 0; ch < 12; ++ch) {
        int k0 = ch * 64;
        {
            #pragma unroll
            for (int i = 0; i < 4; ++i) {
                int kk = cc * 16 + i * 4;
                float4 va = *(const float4*)(zA + k0 + kk);
                float4 vb = *(const float4*)(zB + k0 + kk);
                at[kk + 0][rr] = (1.0f - w) * va.x + w * vb.x;
                at[kk + 1][rr] = (1.0f - w) * va.y + w * vb.y;
                at[kk + 2][rr] = (1.0f - w) * va.z + w * vb.z;
                at[kk + 3][rr] = (1.0f - w) * va.w + w * vb.w;
            }
        }
        {
            const float4* src = (const float4*)(W_out + (size_t)(ot * 64 + rr) * HH + k0 + cc * 16);
            #pragma unroll
            for (int i = 0; i < 4; ++i) {
                float4 v = src[i];
                int kk = cc * 16 + i * 4;
                bt[kk + 0][rr] = v.x; bt[kk + 1][rr] = v.y;
                bt[kk + 2][rr] = v.z; bt[kk + 3][rr] = v.w;
            }
        }
        __syncthreads();
        #pragma unroll
        for (int kk = 0; kk < 64; ++kk) {
            float4 aa = *(const float4*)&at[kk][m0];
            float4 ba = *(const float4*)&bt[kk][o0];
            acc[0][0] += aa.x * ba.x; acc[0][1] += aa.x * ba.y;
            acc[0][2] += aa.x * ba.z; acc[0][3] += aa.x * ba.w;
            acc[1][0] += aa.y * ba.x; acc[1][1] += aa.y * ba.y;
            acc[1][2] += aa.y * ba.z; acc[1][3] += aa.y * ba.w;
            acc[2][0] += aa.z * ba.x; acc[2][1] += aa.z * ba.y;
            acc[2][2] += aa.z * ba.z; acc[2][3] += aa.z * ba.w;
            acc[3][0] += aa.w * ba.x; acc[3][1] += aa.w * ba.y;
            acc[3][2] += aa.w * ba.z; acc[3][3] += aa.w * ba.w;
        }
        __syncthreads();
    }
    #pragma unroll
    for (int i = 0; i < 4; ++i) {
        float* dst = out + (size_t)(mt * 64 + m0 + i) * OO + ot * 64 + o0;
        #pragma unroll
        for (int jj = 0; jj < 4; ++jj)
            dst[jj] = acc[i][jj] + b_out[ot * 64 + o0 + jj];
    }
}

// ---------------------------------------------------------------------------
extern "C" void kernel_launch(void* const* d_in, const int* in_sizes, int n_in,
                              void* d_out, int out_size, void* d_ws, size_t ws_size,
                              hipStream_t stream) {
    const float* traj  = (const float*)d_in[0];
    const float* W_lin = (const float*)d_in[2];
    const float* b_lin = (const float*)d_in[3];
    const float* W_out = (const float*)d_in[4];
    const float* b_out = (const float*)d_in[5];
    const float* W_z0  = (const float*)d_in[6];
    const float* b_z0  = (const float*)d_in[7];

    float* ws = (float*)d_ws;
    float* p  = ws + WS_P;
    float* q  = ws + WS_Q;
    float* pT = ws + WS_PT;
    float* qT = ws + WS_QT;
    float* pb = ws + WS_PB;
    float* qb = ws + WS_QB;
    float* zg = ws + WS_ZG;

    float g[NSTEPS + 1];
    for (int k = 0; k <= NSTEPS; ++k) g[k] = (float)k * 0.05f;
    g[NSTEPS] = 1.0f;

    bool mfma_path = ws_size >= (size_t)WS_MFMA_END * 4;

    if (mfma_path) {
        float* Y = ws + WS_Y;
        unsigned short* zghi = (unsigned short*)(ws + WS_ZGHI);
        unsigned short* zglo = (unsigned short*)(ws + WS_ZGLO);
        unsigned short* Whi  = (unsigned short*)(ws + WS_WHI);
        unsigned short* Wlo  = (unsigned short*)(ws + WS_WLO);

        k_spline<<<16, 256, 0, stream>>>(traj, p, q, pT, qT);
        k_init<<<BB, 256, 0, stream>>>(traj, W_z0, b_z0, b_lin, p, q, zg, pb, qb,
                                       zghi, zglo);
        k_wsplit<<<18432, 256, 0, stream>>>(W_lin, Whi, Wlo);

        for (int k = 0; k < NSTEPS; ++k) {
            float t  = g[k];
            float dt = g[k + 1] - g[k];
            k_step_mfma<<<256, 768, 0, stream>>>(
                Whi, Wlo,
                zghi + (size_t)k * (BB * HH), zglo + (size_t)k * (BB * HH),
                pT, qT, pb, qb,
                zg + (size_t)k * (BB * HH), zg + (size_t)(k + 1) * (BB * HH),
                zghi + (size_t)(k + 1) * (BB * HH), zglo + (size_t)(k + 1) * (BB * HH),
                t, dt);
        }
        k_ygemm<<<dim3(21, 4), 256, 0, stream>>>(zg, W_out, b_out, Y);
        k_interp<<<2048, 256, 0, stream>>>(Y, (float*)d_out);
    } else {
        float* part = ws + WS_PART;
        size_t base_bytes = (size_t)WS_PART * 4;
        int S = 64;
        while (S > 1 && base_bytes + (size_t)S * (BB * HH) * 4 > ws_size) S >>= 1;
        int dpb = 64 / S;

        k_spline<<<16, 256, 0, stream>>>(traj, p, q, pT, qT);
        k_init<<<BB, 256, 0, stream>>>(traj, W_z0, b_z0, b_lin, p, q, zg, pb, qb,
                                       nullptr, nullptr);
        for (int k = 0; k < NSTEPS; ++k) {
            float t  = g[k];
            float dt = g[k + 1] - g[k];
            const float* zprev = zg + (size_t)k * (BB * HH);
            float* znext       = zg + (size_t)(k + 1) * (BB * HH);
            k_step_gemm<<<dim3(12, S), 256, 0, stream>>>(W_lin, p, q, zprev, part, dpb, t);
            k_step_update<<<192, 256, 0, stream>>>(part, pb, qb, zprev, znext, S, t, dt);
        }
        k_out<<<dim3(128, 4), 256, 0, stream>>>(zg, W_out, b_out, (float*)d_out);
    }
}